// Round 6
// baseline (682.872 us; speedup 1.0000x reference)
//
#include <hip/hip_runtime.h>
#include <hip/hip_fp16.h>

#define NN 100000
#define EE 1200000
#define DD 64
#define CC 40
#define KK 16
#define BSZ 196                          // nodes per sort bucket
#define NBK 512                          // buckets (512*196 = 100352 >= NN)
#define TCAP 3072                        // tmp capacity per bucket (mean 2352, ~15 sigma)
#define EPB 4096                         // edges per phase-A block
#define ABLK ((EE + EPB - 1) / EPB)      // 293

// ---------- cursor init: cursor[b] = b*TCAP ----------
__global__ __launch_bounds__(512) void curinit_kernel(int* __restrict__ cursor) {
    int b = threadIdx.x;
    if (b < NBK) cursor[b] = b * TCAP;
}

// ---------- sort phase A: LDS-bin 4096 edges into 512 buckets, write runs ----------
// tmp has fixed per-bucket segments [b*TCAP, (b+1)*TCAP). Runs are coalesced,
// each line written whole from one CU -> no E*64B write amplification.
__global__ __launch_bounds__(256) void sortA_kernel(const int* __restrict__ src,
                                                    const int* __restrict__ dst,
                                                    int* __restrict__ cursor,
                                                    int2* __restrict__ tmp) {
    __shared__ int2 stg[EPB];                 // 32KB
    __shared__ int hist[NBK], loff[NBK], lcur[NBK], gbase[NBK];  // 8KB
    int t = threadIdx.x;
    long e0 = (long)blockIdx.x * EPB;
    int n = (int)((EE - e0 < EPB) ? (EE - e0) : EPB);
    for (int j = t; j < NBK; j += 256) hist[j] = 0;
    __syncthreads();
    int d[16], sx[16];
#pragma unroll
    for (int j = 0; j < 16; ++j) {
        int i = t + j * 256;
        if (i < n) {
            d[j] = dst[e0 + i];
            sx[j] = src[e0 + i];
            atomicAdd(&hist[d[j] / BSZ], 1);
        } else d[j] = -1;
    }
    __syncthreads();
    // exclusive scan of hist[512] with 256 threads (2 elems each)
    int c0 = hist[2 * t], c1 = hist[2 * t + 1];
    int s2 = c0 + c1;
    __syncthreads();
    loff[t] = s2;  // temp: per-thread sums in loff[0..255]
    __syncthreads();
    for (int off = 1; off < 256; off <<= 1) {
        int u = (t >= off) ? loff[t - off] : 0;
        __syncthreads();
        loff[t] += u;
        __syncthreads();
    }
    int excl = loff[t] - s2;
    __syncthreads();  // done with temp usage
    loff[2 * t] = excl;          loff[2 * t + 1] = excl + c0;
    lcur[2 * t] = excl;          lcur[2 * t + 1] = excl + c0;
    gbase[2 * t]     = atomicAdd(&cursor[2 * t], c0);
    gbase[2 * t + 1] = atomicAdd(&cursor[2 * t + 1], c1);
    __syncthreads();
#pragma unroll
    for (int j = 0; j < 16; ++j) {
        if (d[j] >= 0) {
            int b = d[j] / BSZ;
            int p = atomicAdd(&lcur[b], 1);
            stg[p] = make_int2(d[j], sx[j]);
        }
    }
    __syncthreads();
    for (int i = t; i < n; i += 256) {
        int2 r = stg[i];
        int b = r.x / BSZ;
        int pos = gbase[b] + (i - loff[b]);
        if (pos < (b + 1) * TCAP) tmp[pos] = r;  // overflow guard (never hit, 15 sigma)
    }
}

// ---------- bucket-base scan: bbase = exclusive scan of (cursor[b]-b*TCAP) ----------
__global__ __launch_bounds__(512) void bscan_kernel(const int* __restrict__ cursor,
                                                    int* __restrict__ bbase,
                                                    int* __restrict__ row_ptr) {
    __shared__ int sm[512];
    int t = threadIdx.x;
    int v = (t < NBK) ? (cursor[t] - t * TCAP) : 0;
    sm[t] = v;
    __syncthreads();
    for (int off = 1; off < 512; off <<= 1) {
        int u = (t >= off) ? sm[t - off] : 0;
        __syncthreads();
        sm[t] += u;
        __syncthreads();
    }
    if (t < NBK) bbase[t] = sm[t] - v;
    if (t == 511) row_ptr[NN] = sm[511];  // == EE
}

// ---------- sort phase B: counting sort within bucket; emits er2 (src,dst),
// per-node dinv, and row_ptr. Coalesced final write from one CU. ----------
__global__ __launch_bounds__(256) void sortB_kernel(const int2* __restrict__ tmp,
                                                    const int* __restrict__ cursor,
                                                    const int* __restrict__ bbase,
                                                    float* __restrict__ dinv,
                                                    int* __restrict__ row_ptr,
                                                    int2* __restrict__ er2) {
    __shared__ int2 se[TCAP];     // 24KB
    __shared__ int2 so[TCAP];     // 24KB
    __shared__ int hist[256], lcur[256];
    int b = blockIdx.x;
    int n0 = b * BSZ;
    if (n0 >= NN) return;
    int n1 = n0 + BSZ; if (n1 > NN) n1 = NN;
    int nb = n1 - n0;
    int t = threadIdx.x;
    int cnt = cursor[b] - b * TCAP;
    int base = bbase[b];
    hist[t] = 0;
    __syncthreads();
    for (int i = t; i < cnt; i += 256) {
        int2 r = tmp[b * TCAP + i];
        se[i] = r;
        atomicAdd(&hist[r.x - n0], 1);
    }
    __syncthreads();
    if (t < nb) dinv[n0 + t] = rsqrtf((float)(hist[t] + 1));  // +1 self-loop
    // exclusive scan of hist[256]
    int v = hist[t];
    lcur[t] = v;
    __syncthreads();
    for (int off = 1; off < 256; off <<= 1) {
        int u = (t >= off) ? lcur[t - off] : 0;
        __syncthreads();
        lcur[t] += u;
        __syncthreads();
    }
    int excl = lcur[t] - v;
    __syncthreads();
    lcur[t] = excl;
    if (t < nb) row_ptr[n0 + t] = base + excl;
    __syncthreads();
    for (int i = t; i < cnt; i += 256) {
        int2 r = se[i];
        int ln = r.x - n0;
        int pos = atomicAdd(&lcur[ln], 1);
        so[pos] = make_int2(r.y, r.x);  // (src, dst)
    }
    __syncthreads();
    for (int i = t; i < cnt; i += 256) er2[base + i] = so[i];  // coalesced
}

// ---------- weight fill: er2 (src,dst) -> packed 4B records ----------
// rec = src (17 bits) | fp16-bits-of-w-sans-sign (15 bits) << 17
__global__ __launch_bounds__(256) void wfill_kernel(const int2* __restrict__ er2,
                                                    const float* __restrict__ dinv,
                                                    unsigned int* __restrict__ er4) {
    int i = blockIdx.x * 256 + threadIdx.x;
    if (i >= EE) return;
    int2 r = er2[i];
    float w = dinv[r.y] * dinv[r.x];
    unsigned short hb = __half_as_ushort(__float2half_rn(w)) & 0x7FFF;
    er4[i] = (unsigned int)r.x | ((unsigned int)hb << 17);
}

// ---------- feat (fp32) -> x0 (fp16 rows [N][64]) ----------
__global__ __launch_bounds__(256) void cvt_kernel(const float2* __restrict__ feat2,
                                                  __half2* __restrict__ xh) {
    int i = blockIdx.x * 256 + threadIdx.x;
    if (i < NN * 32) {
        float2 f = feat2[i];
        xh[i] = __floats2half2_rn(f.x, f.y);
    }
}

// ---------- fused SpMM (pull, fp16 x, 4B packed edges) + SSGC h-update ----------
// 8 lanes/node (float4 = 8 halves each), 8 nodes/wave, unroll x8.
// mode: 0 = no h; 1 = h init (j==10); 2 = h accumulate; 3 = final (h acc +
// analytic feat term, skip x_out store)
__global__ __launch_bounds__(256) void spmm_step(
    const float4* __restrict__ x, float4* __restrict__ x_out,
    float4* __restrict__ h4, const float4* __restrict__ feat4,
    const int* __restrict__ row_ptr, const unsigned int* __restrict__ er4,
    const float* __restrict__ dinv, int mode) {
    int g = (blockIdx.x * 256 + threadIdx.x) >> 3;  // node; grid exact NN*8 threads
    int li = threadIdx.x & 7;                       // owns dims [8li, 8li+8)
    int beg = row_ptr[g], end = row_ptr[g + 1];
    float di = dinv[g];
    float w0 = di * di;
    int base = g * 8 + li;
    float4 sv = x[base];
    float a0, a1, a2, a3, a4, a5, a6, a7;
    {
        const __half2* hp = (const __half2*)&sv;
        float2 f0 = __half22float2(hp[0]), f1 = __half22float2(hp[1]);
        float2 f2 = __half22float2(hp[2]), f3 = __half22float2(hp[3]);
        a0 = w0 * f0.x; a1 = w0 * f0.y; a2 = w0 * f1.x; a3 = w0 * f1.y;
        a4 = w0 * f2.x; a5 = w0 * f2.y; a6 = w0 * f3.x; a7 = w0 * f3.y;
    }
#define ACC8(WW, V)                                                         \
    {                                                                       \
        const __half2* hp = (const __half2*)&(V);                           \
        float2 f0 = __half22float2(hp[0]), f1 = __half22float2(hp[1]);      \
        float2 f2 = __half22float2(hp[2]), f3 = __half22float2(hp[3]);      \
        a0 = fmaf((WW), f0.x, a0); a1 = fmaf((WW), f0.y, a1);               \
        a2 = fmaf((WW), f1.x, a2); a3 = fmaf((WW), f1.y, a3);               \
        a4 = fmaf((WW), f2.x, a4); a5 = fmaf((WW), f2.y, a5);               \
        a6 = fmaf((WW), f3.x, a6); a7 = fmaf((WW), f3.y, a7);               \
    }
    int e = beg;
    int e8 = beg + ((end - beg) & ~7);
    for (; e < e8; e += 8) {  // 8 gathers in flight per lane
        unsigned int q[8];
        float4 v[8];
#pragma unroll
        for (int j = 0; j < 8; ++j) q[j] = er4[e + j];
#pragma unroll
        for (int j = 0; j < 8; ++j) v[j] = x[(int)(q[j] & 0x1FFFFu) * 8 + li];
#pragma unroll
        for (int j = 0; j < 8; ++j) {
            float wj = __half2float(__ushort_as_half((unsigned short)(q[j] >> 17)));
            ACC8(wj, v[j]);
        }
    }
    for (; e < end; ++e) {
        unsigned int q = er4[e];
        float4 v = x[(int)(q & 0x1FFFFu) * 8 + li];
        float wj = __half2float(__ushort_as_half((unsigned short)(q >> 17)));
        ACC8(wj, v);
    }
#undef ACC8
    if (mode != 3) {
        float4 ov;
        __half2* op = (__half2*)&ov;
        op[0] = __floats2half2_rn(a0, a1);
        op[1] = __floats2half2_rn(a2, a3);
        op[2] = __floats2half2_rn(a4, a5);
        op[3] = __floats2half2_rn(a6, a7);
        x_out[base] = ov;
    }
    if (mode) {
        int hb = g * 16 + li * 2;
        float4 h0, h1;
        if (mode == 1) {  // init: h was 0
            h0.x = 0.95f * a0 * (1.0f / 16.0f); h0.y = 0.95f * a1 * (1.0f / 16.0f);
            h0.z = 0.95f * a2 * (1.0f / 16.0f); h0.w = 0.95f * a3 * (1.0f / 16.0f);
            h1.x = 0.95f * a4 * (1.0f / 16.0f); h1.y = 0.95f * a5 * (1.0f / 16.0f);
            h1.z = 0.95f * a6 * (1.0f / 16.0f); h1.w = 0.95f * a7 * (1.0f / 16.0f);
        } else {
            h0 = h4[hb]; h1 = h4[hb + 1];
            h0.x = (h0.x + 0.95f * a0) * (1.0f / 16.0f);
            h0.y = (h0.y + 0.95f * a1) * (1.0f / 16.0f);
            h0.z = (h0.z + 0.95f * a2) * (1.0f / 16.0f);
            h0.w = (h0.w + 0.95f * a3) * (1.0f / 16.0f);
            h1.x = (h1.x + 0.95f * a4) * (1.0f / 16.0f);
            h1.y = (h1.y + 0.95f * a5) * (1.0f / 16.0f);
            h1.z = (h1.z + 0.95f * a6) * (1.0f / 16.0f);
            h1.w = (h1.w + 0.95f * a7) * (1.0f / 16.0f);
        }
        if (mode == 3) {
            const float FC = 0.05f / 15.0f;  // analytic sum of all 16 feat terms
            float4 f0 = feat4[hb], f1 = feat4[hb + 1];
            h0.x = fmaf(FC, f0.x, h0.x); h0.y = fmaf(FC, f0.y, h0.y);
            h0.z = fmaf(FC, f0.z, h0.z); h0.w = fmaf(FC, f0.w, h0.w);
            h1.x = fmaf(FC, f1.x, h1.x); h1.y = fmaf(FC, f1.y, h1.y);
            h1.z = fmaf(FC, f1.z, h1.z); h1.w = fmaf(FC, f1.w, h1.w);
        }
        h4[hb] = h0; h4[hb + 1] = h1;
    }
}

// ---------- FC epilogue ----------
__global__ __launch_bounds__(256) void fc_kernel(const float* __restrict__ h,
                                                 const float* __restrict__ W,
                                                 const float* __restrict__ b,
                                                 float* __restrict__ out) {
    __shared__ float Ws[CC * 68];
    __shared__ float bs[CC];
    for (int j = threadIdx.x; j < CC * DD; j += 256) {
        int c = j >> 6, d = j & 63;
        Ws[c * 68 + d] = W[j];
    }
    if (threadIdx.x < CC) bs[threadIdx.x] = b[threadIdx.x];
    __syncthreads();
    int idx = blockIdx.x * 256 + threadIdx.x;
    if (idx >= NN * CC) return;
    int i = idx / CC, c = idx - i * CC;
    const float4* h4 = (const float4*)(h + (long)i * DD);
    const float* wr = Ws + c * 68;
    float acc = bs[c];
#pragma unroll
    for (int d2 = 0; d2 < 16; ++d2) {
        float4 a = h4[d2];
        acc = fmaf(a.x, wr[d2 * 4 + 0], acc);
        acc = fmaf(a.y, wr[d2 * 4 + 1], acc);
        acc = fmaf(a.z, wr[d2 * 4 + 2], acc);
        acc = fmaf(a.w, wr[d2 * 4 + 3], acc);
    }
    out[idx] = acc;
}

extern "C" void kernel_launch(void* const* d_in, const int* in_sizes, int n_in,
                              void* d_out, int out_size, void* d_ws, size_t ws_size,
                              hipStream_t stream) {
    const float* feat = (const float*)d_in[0];
    const float* W    = (const float*)d_in[1];
    const float* b    = (const float*)d_in[2];
    const int*   src  = (const int*)d_in[3];
    const int*   dst  = (const int*)d_in[4];
    float* out = (float*)d_out;

    char* p = (char*)d_ws;
    auto alloc = [&](size_t bytes) {
        char* r = p;
        p += (bytes + 255) & ~(size_t)255;
        return r;
    };
    float*        dinv    = (float*)alloc((size_t)NN * sizeof(float));
    int*          row_ptr = (int*)alloc((size_t)(NN + 1) * sizeof(int));
    int*          cursor  = (int*)alloc((size_t)NBK * sizeof(int));
    int*          bbase   = (int*)alloc((size_t)NBK * sizeof(int));
    int2*         tmp     = (int2*)alloc((size_t)NBK * TCAP * sizeof(int2));  // 12.6MB
    int2*         er2     = (int2*)alloc((size_t)EE * sizeof(int2));          // 9.6MB
    unsigned int* er4     = (unsigned int*)alloc((size_t)EE * sizeof(int));   // 4.8MB
    float4*       xh0     = (float4*)alloc((size_t)NN * 8 * sizeof(float4));  // 12.8MB
    float4*       xh1     = (float4*)alloc((size_t)NN * 8 * sizeof(float4));  // 12.8MB
    float*        h       = (float*)alloc((size_t)NN * DD * sizeof(float));   // 25.6MB

    curinit_kernel<<<1, 512, 0, stream>>>(cursor);
    sortA_kernel<<<ABLK, 256, 0, stream>>>(src, dst, cursor, tmp);
    bscan_kernel<<<1, 512, 0, stream>>>(cursor, bbase, row_ptr);
    sortB_kernel<<<NBK, 256, 0, stream>>>(tmp, cursor, bbase, dinv, row_ptr, er2);
    wfill_kernel<<<(EE + 255) / 256, 256, 0, stream>>>(er2, dinv, er4);
    cvt_kernel<<<(NN * 32 + 255) / 256, 256, 0, stream>>>((const float2*)feat,
                                                          (__half2*)xh0);

    const float4* xs = xh0;
    float4* xd = xh1;
    for (int j = 0; j < KK; ++j) {
        int mode = (j < 10) ? 0 : ((j == 10) ? 1 : ((j == KK - 1) ? 3 : 2));
        spmm_step<<<3125, 256, 0, stream>>>(xs, xd, (float4*)h, (const float4*)feat,
                                            row_ptr, er4, dinv, mode);
        const float4* t = xd;
        xd = (xd == xh0) ? xh1 : xh0;
        xs = t;
    }
    fc_kernel<<<(NN * CC + 255) / 256, 256, 0, stream>>>(h, W, b, out);
}

// Round 7
// 625.958 us; speedup vs baseline: 1.0909x; 1.0909x over previous
//
#include <hip/hip_runtime.h>
#include <hip/hip_fp16.h>

#define NN 100000
#define EE 1200000
#define DD 64
#define CC 40
#define KK 16
#define BSZ 196                          // nodes per sort bucket
#define NBK 512                          // buckets (512*196 = 100352 >= NN)
#define TCAP 3072                        // tmp capacity per bucket (mean 2352, ~15 sigma)
#define EPB 4096                         // edges per phase-A block
#define ABLK ((EE + EPB - 1) / EPB)      // 293

struct __align__(8) ERec { int c; float w; };

// ---------- cursor init: cursor[b] = b*TCAP ----------
__global__ __launch_bounds__(512) void curinit_kernel(int* __restrict__ cursor) {
    int b = threadIdx.x;
    if (b < NBK) cursor[b] = b * TCAP;
}

// ---------- sort phase A: LDS-bin 4096 edges into 512 buckets, write runs ----------
// tmp has fixed per-bucket segments [b*TCAP, (b+1)*TCAP). Runs are coalesced,
// each line written whole from one CU -> no E*64B write amplification.
__global__ __launch_bounds__(256) void sortA_kernel(const int* __restrict__ src,
                                                    const int* __restrict__ dst,
                                                    int* __restrict__ cursor,
                                                    int2* __restrict__ tmp) {
    __shared__ int2 stg[EPB];                 // 32KB
    __shared__ int hist[NBK], loff[NBK], lcur[NBK], gbase[NBK];  // 8KB
    int t = threadIdx.x;
    long e0 = (long)blockIdx.x * EPB;
    int n = (int)((EE - e0 < EPB) ? (EE - e0) : EPB);
    for (int j = t; j < NBK; j += 256) hist[j] = 0;
    __syncthreads();
    int d[16], sx[16];
#pragma unroll
    for (int j = 0; j < 16; ++j) {
        int i = t + j * 256;
        if (i < n) {
            d[j] = dst[e0 + i];
            sx[j] = src[e0 + i];
            atomicAdd(&hist[d[j] / BSZ], 1);
        } else d[j] = -1;
    }
    __syncthreads();
    // exclusive scan of hist[512] with 256 threads (2 elems each)
    int c0 = hist[2 * t], c1 = hist[2 * t + 1];
    int s2 = c0 + c1;
    __syncthreads();
    loff[t] = s2;  // temp: per-thread sums in loff[0..255]
    __syncthreads();
    for (int off = 1; off < 256; off <<= 1) {
        int u = (t >= off) ? loff[t - off] : 0;
        __syncthreads();
        loff[t] += u;
        __syncthreads();
    }
    int excl = loff[t] - s2;
    __syncthreads();  // done with temp usage
    loff[2 * t] = excl;          loff[2 * t + 1] = excl + c0;
    lcur[2 * t] = excl;          lcur[2 * t + 1] = excl + c0;
    gbase[2 * t]     = atomicAdd(&cursor[2 * t], c0);
    gbase[2 * t + 1] = atomicAdd(&cursor[2 * t + 1], c1);
    __syncthreads();
#pragma unroll
    for (int j = 0; j < 16; ++j) {
        if (d[j] >= 0) {
            int b = d[j] / BSZ;
            int p = atomicAdd(&lcur[b], 1);
            stg[p] = make_int2(d[j], sx[j]);
        }
    }
    __syncthreads();
    for (int i = t; i < n; i += 256) {
        int2 r = stg[i];
        int b = r.x / BSZ;
        int pos = gbase[b] + (i - loff[b]);
        if (pos < (b + 1) * TCAP) tmp[pos] = r;  // overflow guard (never hit, 15 sigma)
    }
}

// ---------- bucket-base scan: bbase = exclusive scan of (cursor[b]-b*TCAP) ----------
__global__ __launch_bounds__(512) void bscan_kernel(const int* __restrict__ cursor,
                                                    int* __restrict__ bbase,
                                                    int* __restrict__ row_ptr) {
    __shared__ int sm[512];
    int t = threadIdx.x;
    int v = (t < NBK) ? (cursor[t] - t * TCAP) : 0;
    sm[t] = v;
    __syncthreads();
    for (int off = 1; off < 512; off <<= 1) {
        int u = (t >= off) ? sm[t - off] : 0;
        __syncthreads();
        sm[t] += u;
        __syncthreads();
    }
    if (t < NBK) bbase[t] = sm[t] - v;
    if (t == 511) row_ptr[NN] = sm[511];  // == EE
}

// ---------- sort phase B: counting sort within bucket; emits er2 (src,dst),
// per-node dinv, and row_ptr. Coalesced final write from one CU. ----------
__global__ __launch_bounds__(256) void sortB_kernel(const int2* __restrict__ tmp,
                                                    const int* __restrict__ cursor,
                                                    const int* __restrict__ bbase,
                                                    float* __restrict__ dinv,
                                                    int* __restrict__ row_ptr,
                                                    int2* __restrict__ er2) {
    __shared__ int2 se[TCAP];     // 24KB
    __shared__ int2 so[TCAP];     // 24KB
    __shared__ int hist[256], lcur[256];
    int b = blockIdx.x;
    int n0 = b * BSZ;
    if (n0 >= NN) return;
    int n1 = n0 + BSZ; if (n1 > NN) n1 = NN;
    int nb = n1 - n0;
    int t = threadIdx.x;
    int cnt = cursor[b] - b * TCAP;
    int base = bbase[b];
    hist[t] = 0;
    __syncthreads();
    for (int i = t; i < cnt; i += 256) {
        int2 r = tmp[b * TCAP + i];
        se[i] = r;
        atomicAdd(&hist[r.x - n0], 1);
    }
    __syncthreads();
    if (t < nb) dinv[n0 + t] = rsqrtf((float)(hist[t] + 1));  // +1 self-loop
    // exclusive scan of hist[256]
    int v = hist[t];
    lcur[t] = v;
    __syncthreads();
    for (int off = 1; off < 256; off <<= 1) {
        int u = (t >= off) ? lcur[t - off] : 0;
        __syncthreads();
        lcur[t] += u;
        __syncthreads();
    }
    int excl = lcur[t] - v;
    __syncthreads();
    lcur[t] = excl;
    if (t < nb) row_ptr[n0 + t] = base + excl;
    __syncthreads();
    for (int i = t; i < cnt; i += 256) {
        int2 r = se[i];
        int ln = r.x - n0;
        int pos = atomicAdd(&lcur[ln], 1);
        so[pos] = make_int2(r.y, r.x);  // (src, dst)
    }
    __syncthreads();
    for (int i = t; i < cnt; i += 256) er2[base + i] = so[i];  // coalesced
}

// ---------- weight fill: er2 (src,dst) -> ERec (src, fp32 w) ----------
__global__ __launch_bounds__(256) void wfill_kernel(const int2* __restrict__ er2,
                                                    const float* __restrict__ dinv,
                                                    int2* __restrict__ er) {
    int i = blockIdx.x * 256 + threadIdx.x;
    if (i >= EE) return;
    int2 r = er2[i];
    float w = dinv[r.y] * dinv[r.x];
    er[i] = make_int2(r.x, __float_as_int(w));
}

// ---------- feat (fp32) -> x0 (fp16 rows [N][64]) ----------
__global__ __launch_bounds__(256) void cvt_kernel(const float2* __restrict__ feat2,
                                                  __half2* __restrict__ xh) {
    int i = blockIdx.x * 256 + threadIdx.x;
    if (i < NN * 32) {
        float2 f = feat2[i];
        xh[i] = __floats2half2_rn(f.x, f.y);
    }
}

// ---------- fused SpMM (pull, fp16 x) + SSGC h-update ----------
// 8 lanes/node (float4 = 8 halves each), 8 nodes/wave, unroll x4.
// mode: 0 = no h; 1 = h init (j==10); 2 = h accumulate; 3 = final (h acc +
// analytic feat term, skip x_out store)
__global__ __launch_bounds__(256) void spmm_step(
    const float4* __restrict__ x, float4* __restrict__ x_out,
    float4* __restrict__ h4, const float4* __restrict__ feat4,
    const int* __restrict__ row_ptr, const ERec* __restrict__ er,
    const float* __restrict__ dinv, int mode) {
    int g = (blockIdx.x * 256 + threadIdx.x) >> 3;  // node; grid exact NN*8 threads
    int li = threadIdx.x & 7;                       // owns dims [8li, 8li+8)
    int beg = row_ptr[g], end = row_ptr[g + 1];
    float di = dinv[g];
    float w0 = di * di;
    int base = g * 8 + li;
    float4 sv = x[base];
    float a0, a1, a2, a3, a4, a5, a6, a7;
    {
        const __half2* hp = (const __half2*)&sv;
        float2 f0 = __half22float2(hp[0]), f1 = __half22float2(hp[1]);
        float2 f2 = __half22float2(hp[2]), f3 = __half22float2(hp[3]);
        a0 = w0 * f0.x; a1 = w0 * f0.y; a2 = w0 * f1.x; a3 = w0 * f1.y;
        a4 = w0 * f2.x; a5 = w0 * f2.y; a6 = w0 * f3.x; a7 = w0 * f3.y;
    }
#define ACC8(R, V)                                                          \
    {                                                                       \
        const __half2* hp = (const __half2*)&(V);                           \
        float2 f0 = __half22float2(hp[0]), f1 = __half22float2(hp[1]);      \
        float2 f2 = __half22float2(hp[2]), f3 = __half22float2(hp[3]);      \
        a0 = fmaf((R).w, f0.x, a0); a1 = fmaf((R).w, f0.y, a1);             \
        a2 = fmaf((R).w, f1.x, a2); a3 = fmaf((R).w, f1.y, a3);             \
        a4 = fmaf((R).w, f2.x, a4); a5 = fmaf((R).w, f2.y, a5);             \
        a6 = fmaf((R).w, f3.x, a6); a7 = fmaf((R).w, f3.y, a7);             \
    }
    int e = beg;
    int e4 = beg + ((end - beg) & ~3);
    for (; e < e4; e += 4) {
        ERec r0 = er[e], r1 = er[e + 1], r2 = er[e + 2], r3 = er[e + 3];
        float4 v0 = x[r0.c * 8 + li];
        float4 v1 = x[r1.c * 8 + li];
        float4 v2 = x[r2.c * 8 + li];
        float4 v3 = x[r3.c * 8 + li];
        ACC8(r0, v0); ACC8(r1, v1); ACC8(r2, v2); ACC8(r3, v3);
    }
    for (; e < end; ++e) {
        ERec r = er[e];
        float4 v = x[r.c * 8 + li];
        ACC8(r, v);
    }
#undef ACC8
    if (mode != 3) {
        float4 ov;
        __half2* op = (__half2*)&ov;
        op[0] = __floats2half2_rn(a0, a1);
        op[1] = __floats2half2_rn(a2, a3);
        op[2] = __floats2half2_rn(a4, a5);
        op[3] = __floats2half2_rn(a6, a7);
        x_out[base] = ov;
    }
    if (mode) {
        int hb = g * 16 + li * 2;
        float4 h0, h1;
        if (mode == 1) {  // init: h was 0
            h0.x = 0.95f * a0 * (1.0f / 16.0f); h0.y = 0.95f * a1 * (1.0f / 16.0f);
            h0.z = 0.95f * a2 * (1.0f / 16.0f); h0.w = 0.95f * a3 * (1.0f / 16.0f);
            h1.x = 0.95f * a4 * (1.0f / 16.0f); h1.y = 0.95f * a5 * (1.0f / 16.0f);
            h1.z = 0.95f * a6 * (1.0f / 16.0f); h1.w = 0.95f * a7 * (1.0f / 16.0f);
        } else {
            h0 = h4[hb]; h1 = h4[hb + 1];
            h0.x = (h0.x + 0.95f * a0) * (1.0f / 16.0f);
            h0.y = (h0.y + 0.95f * a1) * (1.0f / 16.0f);
            h0.z = (h0.z + 0.95f * a2) * (1.0f / 16.0f);
            h0.w = (h0.w + 0.95f * a3) * (1.0f / 16.0f);
            h1.x = (h1.x + 0.95f * a4) * (1.0f / 16.0f);
            h1.y = (h1.y + 0.95f * a5) * (1.0f / 16.0f);
            h1.z = (h1.z + 0.95f * a6) * (1.0f / 16.0f);
            h1.w = (h1.w + 0.95f * a7) * (1.0f / 16.0f);
        }
        if (mode == 3) {
            const float FC = 0.05f / 15.0f;  // analytic sum of all 16 feat terms
            float4 f0 = feat4[hb], f1 = feat4[hb + 1];
            h0.x = fmaf(FC, f0.x, h0.x); h0.y = fmaf(FC, f0.y, h0.y);
            h0.z = fmaf(FC, f0.z, h0.z); h0.w = fmaf(FC, f0.w, h0.w);
            h1.x = fmaf(FC, f1.x, h1.x); h1.y = fmaf(FC, f1.y, h1.y);
            h1.z = fmaf(FC, f1.z, h1.z); h1.w = fmaf(FC, f1.w, h1.w);
        }
        h4[hb] = h0; h4[hb + 1] = h1;
    }
}

// ---------- FC epilogue ----------
// Ws stride 65: bank = (65c+d)%32 = (c+d)%32 -> <=2-way across 40 lanes (free).
__global__ __launch_bounds__(256) void fc_kernel(const float* __restrict__ h,
                                                 const float* __restrict__ W,
                                                 const float* __restrict__ b,
                                                 float* __restrict__ out) {
    __shared__ float Ws[CC * 65];  // 10400B
    __shared__ float bs[CC];
    for (int j = threadIdx.x; j < CC * DD; j += 256) {
        int c = j >> 6, d = j & 63;
        Ws[c * 65 + d] = W[j];
    }
    if (threadIdx.x < CC) bs[threadIdx.x] = b[threadIdx.x];
    __syncthreads();
    int idx = blockIdx.x * 256 + threadIdx.x;
    if (idx >= NN * CC) return;
    int i = idx / CC, c = idx - i * CC;
    const float4* h4 = (const float4*)(h + (long)i * DD);
    const float* wr = Ws + c * 65;
    float acc = bs[c];
#pragma unroll
    for (int d2 = 0; d2 < 16; ++d2) {
        float4 a = h4[d2];
        acc = fmaf(a.x, wr[d2 * 4 + 0], acc);
        acc = fmaf(a.y, wr[d2 * 4 + 1], acc);
        acc = fmaf(a.z, wr[d2 * 4 + 2], acc);
        acc = fmaf(a.w, wr[d2 * 4 + 3], acc);
    }
    out[idx] = acc;
}

extern "C" void kernel_launch(void* const* d_in, const int* in_sizes, int n_in,
                              void* d_out, int out_size, void* d_ws, size_t ws_size,
                              hipStream_t stream) {
    const float* feat = (const float*)d_in[0];
    const float* W    = (const float*)d_in[1];
    const float* b    = (const float*)d_in[2];
    const int*   src  = (const int*)d_in[3];
    const int*   dst  = (const int*)d_in[4];
    float* out = (float*)d_out;

    char* p = (char*)d_ws;
    auto alloc = [&](size_t bytes) {
        char* r = p;
        p += (bytes + 255) & ~(size_t)255;
        return r;
    };
    float*   dinv    = (float*)alloc((size_t)NN * sizeof(float));
    int*     row_ptr = (int*)alloc((size_t)(NN + 1) * sizeof(int));
    int*     cursor  = (int*)alloc((size_t)NBK * sizeof(int));
    int*     bbase   = (int*)alloc((size_t)NBK * sizeof(int));
    int2*    tmp     = (int2*)alloc((size_t)NBK * TCAP * sizeof(int2));  // 12.6MB
    int2*    er2     = (int2*)alloc((size_t)EE * sizeof(int2));          // 9.6MB
    int2*    er      = (int2*)alloc((size_t)EE * sizeof(int2));          // 9.6MB
    float4*  xh0     = (float4*)alloc((size_t)NN * 8 * sizeof(float4));  // 12.8MB
    float4*  xh1     = (float4*)alloc((size_t)NN * 8 * sizeof(float4));  // 12.8MB
    float*   h       = (float*)alloc((size_t)NN * DD * sizeof(float));   // 25.6MB

    curinit_kernel<<<1, 512, 0, stream>>>(cursor);
    sortA_kernel<<<ABLK, 256, 0, stream>>>(src, dst, cursor, tmp);
    bscan_kernel<<<1, 512, 0, stream>>>(cursor, bbase, row_ptr);
    sortB_kernel<<<NBK, 256, 0, stream>>>(tmp, cursor, bbase, dinv, row_ptr, er2);
    wfill_kernel<<<(EE + 255) / 256, 256, 0, stream>>>(er2, dinv, er);
    cvt_kernel<<<(NN * 32 + 255) / 256, 256, 0, stream>>>((const float2*)feat,
                                                          (__half2*)xh0);

    const float4* xs = xh0;
    float4* xd = xh1;
    for (int j = 0; j < KK; ++j) {
        int mode = (j < 10) ? 0 : ((j == 10) ? 1 : ((j == KK - 1) ? 3 : 2));
        spmm_step<<<3125, 256, 0, stream>>>(xs, xd, (float4*)h, (const float4*)feat,
                                            row_ptr, (const ERec*)er, dinv, mode);
        const float4* t = xd;
        xd = (xd == xh0) ? xh1 : xh0;
        xs = t;
    }
    fc_kernel<<<(NN * CC + 255) / 256, 256, 0, stream>>>(h, W, b, out);
}